// Round 2
// baseline (1815.647 us; speedup 1.0000x reference)
//
#include <hip/hip_runtime.h>

#define ALPHA_F 0.1f
#define DEPTH 10
#define FEATS 512
#define HID 64
#define CLS 32

// ---------------- degree count (in-degree over dst) ----------------
__global__ __launch_bounds__(256) void k_deg(const int* __restrict__ dst, int E, int N,
                                             unsigned* __restrict__ deg) {
  int i = blockIdx.x * 256 + threadIdx.x;
  if (i >= E) return;
  int d = dst[i];
  if ((unsigned)d < (unsigned)N) atomicAdd(&deg[d], 1u);
}

// ---------------- exclusive scan over deg -> rowst[0..N] (single block) ----------------
__global__ __launch_bounds__(1024) void k_scan(const unsigned* __restrict__ deg, int N,
                                               unsigned* __restrict__ rowst) {
  __shared__ unsigned sums[1024];
  int t = threadIdx.x;
  int chunk = (N + 1023) >> 10;
  int beg = t * chunk;
  int end = min(beg + chunk, N);
  unsigned s = 0;
  for (int i = beg; i < end; ++i) s += deg[i];
  sums[t] = s;
  __syncthreads();
  for (int off = 1; off < 1024; off <<= 1) {
    unsigned v = (t >= off) ? sums[t - off] : 0u;
    __syncthreads();
    sums[t] += v;
    __syncthreads();
  }
  unsigned pre = (t == 0) ? 0u : sums[t - 1];
  for (int i = beg; i < end; ++i) { rowst[i] = pre; pre += deg[i]; }
  if (t == 1023) rowst[N] = pre;  // last thread's pre == grand total
}

// ---------------- CSR fill + edge weight (0.9 folded into norm) ----------------
__global__ __launch_bounds__(256) void k_fill(const int* __restrict__ src,
                                              const int* __restrict__ dst, int E, int N,
                                              const unsigned* __restrict__ deg,
                                              const unsigned* __restrict__ rowst,
                                              unsigned* __restrict__ cnt,
                                              int* __restrict__ col, float* __restrict__ nrm) {
  int e = blockIdx.x * 256 + threadIdx.x;
  if (e >= E) return;
  int s = src[e];
  int d = dst[e];
  if ((unsigned)s >= (unsigned)N || (unsigned)d >= (unsigned)N) return;  // safety guard
  unsigned slot = rowst[d] + atomicAdd(&cnt[d], 1u);
  unsigned us = deg[s]; if (us == 0u) us = 1u;
  unsigned ud = deg[d]; if (ud == 0u) ud = 1u;
  col[slot] = s;
  nrm[slot] = (1.0f - ALPHA_F) * rsqrtf((float)us * (float)ud);
}

// ---------------- fused MLP: h0 = relu(x@W1+b1)@W2+b2 ----------------
// block = 256 threads, 64-row tile. Layer1: 8x2 register tile per thread
// (rows h*8+i, cols c & c+32). K staged in 64-wide LDS chunks.
__global__ __launch_bounds__(256) void k_mlp(const float* __restrict__ x,
                                             const float* __restrict__ W1,
                                             const float* __restrict__ b1,
                                             const float* __restrict__ W2,
                                             const float* __restrict__ b2,
                                             float* __restrict__ h0, int N) {
  __shared__ float XHs[64 * 65];   // Xs (stride 64) during GEMM1, Hs (stride 65) after
  __shared__ float Ws[64 * 64];    // W1 k-chunk
  __shared__ float W2s[64 * 32];
  __shared__ float b1s[64];
  __shared__ float b2s[32];
  int t = threadIdx.x;
  int m0 = blockIdx.x * 64;

  for (int i = t; i < 64 * 32; i += 256) W2s[i] = W2[i];
  if (t < 64) b1s[t] = b1[t];
  if (t < 32) b2s[t] = b2[t];

  int c = t & 31;   // col pair base (c, c+32)
  int h = t >> 5;   // row group 0..7 -> rows h*8+i
  float acc[8][2];
#pragma unroll
  for (int i = 0; i < 8; ++i) { acc[i][0] = 0.f; acc[i][1] = 0.f; }

  for (int k0 = 0; k0 < FEATS; k0 += 64) {
    __syncthreads();
    // stage X tile [64 rows][64 k] and W1 tile [64 k][64 c]: 1024 float4 each
#pragma unroll
    for (int j = 0; j < 4; ++j) {
      int F = j * 256 + t;          // float4 index 0..1023
      int r = F >> 4, q = F & 15;
      int row = m0 + r;
      float4 v = make_float4(0.f, 0.f, 0.f, 0.f);
      if (row < N) v = *(const float4*)(x + (size_t)row * FEATS + k0 + q * 4);
      *(float4*)(XHs + r * 64 + q * 4) = v;
      float4 w = *(const float4*)(W1 + (size_t)(k0 + r) * 64 + q * 4);
      *(float4*)(Ws + r * 64 + q * 4) = w;
    }
    __syncthreads();
#pragma unroll
    for (int k4 = 0; k4 < 16; ++k4) {
      int k = k4 * 4;
      float4 xv[8];
#pragma unroll
      for (int i = 0; i < 8; ++i) xv[i] = *(const float4*)(XHs + (h * 8 + i) * 64 + k);
#pragma unroll
      for (int j = 0; j < 4; ++j) {
        float w0 = Ws[(k + j) * 64 + c];
        float w1 = Ws[(k + j) * 64 + c + 32];
#pragma unroll
        for (int i = 0; i < 8; ++i) {
          float xx = ((const float*)&xv[i])[j];
          acc[i][0] += xx * w0;
          acc[i][1] += xx * w1;
        }
      }
    }
  }
  __syncthreads();
  // bias + relu -> Hs (stride 65 to dodge bank conflicts)
#pragma unroll
  for (int i = 0; i < 8; ++i) {
    int r = h * 8 + i;
    float v0 = acc[i][0] + b1s[c];
    float v1 = acc[i][1] + b1s[c + 32];
    XHs[r * 65 + c] = v0 > 0.f ? v0 : 0.f;
    XHs[r * 65 + c + 32] = v1 > 0.f ? v1 : 0.f;
  }
  __syncthreads();
  // layer 2: thread -> class cc = t&31, rows h*8+i
  int cc = t & 31;
#pragma unroll
  for (int i = 0; i < 8; ++i) {
    int r = h * 8 + i;
    float s = b2s[cc];
#pragma unroll
    for (int k = 0; k < 64; ++k) s += XHs[r * 65 + k] * W2s[k * 32 + cc];
    int row = m0 + r;
    if (row < N) h0[(size_t)row * CLS + cc] = s;
  }
}

// ---------------- one APPNP step: hout = 0.1*h0 + sum_e (0.9*norm)*hin[src] ----------------
// 8 lanes per node, each lane owns 4 classes (float4).
__global__ __launch_bounds__(256) void k_prop(const float* __restrict__ hin,
                                              const float* __restrict__ h0,
                                              const unsigned* __restrict__ rowst,
                                              const int* __restrict__ col,
                                              const float* __restrict__ nrm,
                                              float* __restrict__ hout, int N) {
  int t = blockIdx.x * 256 + threadIdx.x;
  int node = t >> 3;
  if (node >= N) return;
  int l = t & 7;
  unsigned beg = rowst[node];
  unsigned end = rowst[node + 1];
  const float4 h0v = *(const float4*)(h0 + (size_t)node * CLS + l * 4);
  float a0 = ALPHA_F * h0v.x, a1 = ALPHA_F * h0v.y, a2 = ALPHA_F * h0v.z, a3 = ALPHA_F * h0v.w;
#pragma unroll 4
  for (unsigned e = beg; e < end; ++e) {
    int s = col[e];
    float w = nrm[e];
    float4 v = *(const float4*)(hin + (size_t)s * CLS + l * 4);
    a0 += w * v.x; a1 += w * v.y; a2 += w * v.z; a3 += w * v.w;
  }
  *(float4*)(hout + (size_t)node * CLS + l * 4) = make_float4(a0, a1, a2, a3);
}

extern "C" void kernel_launch(void* const* d_in, const int* in_sizes, int n_in,
                              void* d_out, int out_size, void* d_ws, size_t ws_size,
                              hipStream_t stream) {
  const float* x = (const float*)d_in[0];
  const int* edges = (const int*)d_in[1];   // harness stages integer inputs as int32
  const float* W1 = (const float*)d_in[2];
  const float* b1 = (const float*)d_in[3];
  const float* W2 = (const float*)d_in[4];
  const float* b2 = (const float*)d_in[5];
  int N = in_sizes[0] / FEATS;
  int E = in_sizes[1] / 2;
  const int* src = edges;
  const int* dst = edges + E;

  char* ws = (char*)d_ws;
  auto align16 = [](size_t v) { return (v + 15) & ~(size_t)15; };
  size_t o = 0;
  unsigned* deg = (unsigned*)(ws + o);   o = align16(o + (size_t)N * 4);
  unsigned* rowst = (unsigned*)(ws + o); o = align16(o + (size_t)(N + 1) * 4);
  unsigned* cnt = (unsigned*)(ws + o);   o = align16(o + (size_t)N * 4);
  int* col = (int*)(ws + o);             o = align16(o + (size_t)E * 4);
  float* nrm = (float*)(ws + o);         o = align16(o + (size_t)E * 4);
  float* h0 = (float*)(ws + o);          o = align16(o + (size_t)N * CLS * 4);
  float* hA = (float*)(ws + o);          o = align16(o + (size_t)N * CLS * 4);
  // total ws use ~52.4 MB

  hipMemsetAsync(deg, 0, (size_t)N * 4, stream);
  hipMemsetAsync(cnt, 0, (size_t)N * 4, stream);
  k_deg<<<(E + 255) / 256, 256, 0, stream>>>(dst, E, N, deg);
  k_scan<<<1, 1024, 0, stream>>>(deg, N, rowst);
  k_fill<<<(E + 255) / 256, 256, 0, stream>>>(src, dst, E, N, deg, rowst, cnt, col, nrm);
  k_mlp<<<(N + 63) / 64, 256, 0, stream>>>(x, W1, b1, W2, b2, h0, N);

  const float* hin = h0;
  float* outF = (float*)d_out;
  for (int it = 0; it < DEPTH; ++it) {
    float* ho = (it & 1) ? outF : hA;  // it=9 (last, odd) -> d_out
    k_prop<<<((N * 8) + 255) / 256, 256, 0, stream>>>(hin, h0, rowst, col, nrm, ho, N);
    hin = ho;
  }
}